// Round 9
// baseline (544.482 us; speedup 1.0000x reference)
//
#include <hip/hip_runtime.h>

#define IN_DIM 256
#define HID 64
#define SBSH 8             // log2(nodes per super-bucket)
#define SBN 256            // nodes per super-bucket
#define NSB_MAX 512        // LDS array bound (covers N <= 131072)
#define PB 256             // partition blocks (chunk count) — must match p2a/p2b
#define NSLICE 8           // xsb column slices (8 cols = 16 B each); one per XCD

// round-to-nearest-even fp32 -> bf16 bits
static __device__ __forceinline__ unsigned bf16r(float f) {
    unsigned x = __float_as_uint(f);
    return (x + 0x7fffu + ((x >> 16) & 1u)) >> 16;
}

static __device__ __forceinline__ float blo(unsigned u) { return __uint_as_float(u << 16); }
static __device__ __forceinline__ float bhi(unsigned u) { return __uint_as_float(u & 0xffff0000u); }

// ---------------------------------------------------------------------------
// 1) zero the coarse bucket counters (tiny)
__global__ void __launch_bounds__(256) k_zero(int* __restrict__ p, int n) {
    int i = blockIdx.x * 256 + threadIdx.x;
    if (i < n) p[i] = 0;
}

// 2) partition pass A: per-block LDS histogram over super-buckets.
//    Stores blkHist[bucket][block] and accumulates bucketCnt (one atomic per
//    (block,bucket) ~ 100K total). Single edge-list read.
__global__ void __launch_bounds__(256) k_p2a(const int* __restrict__ col,
                                             int* __restrict__ bucketCnt,
                                             int* __restrict__ blkHist, int E, int nsb) {
    __shared__ int hist[NSB_MAX];
    const int tid = threadIdx.x, b = blockIdx.x;
    const int chunkE = (E + PB - 1) / PB;
    const int s = b * chunkE, e = min(s + chunkE, E);
    for (int i = tid; i < nsb; i += 256) hist[i] = 0;
    __syncthreads();
    for (int j = s + tid; j < e; j += 256) atomicAdd(&hist[col[j] >> SBSH], 1);
    __syncthreads();
    for (int i = tid; i < nsb; i += 256) {
        int h = hist[i];
        blkHist[i * PB + b] = h;
        if (h) atomicAdd(&bucketCnt[i], h);
    }
}

// 3) single-block exclusive scan of bucketCnt[nsb] -> bucketOff; seeds rowptr[N]=E.
__global__ void __launch_bounds__(256) k_scanB(const int* __restrict__ bucketCnt,
                                               int* __restrict__ bucketOff,
                                               int* __restrict__ rowptr,
                                               int nsb, int N, int E) {
    __shared__ int tmp[256];
    const int tid = threadIdx.x;
    const int PT = (nsb + 255) >> 8;
    int v[8];
    int s = 0;
    for (int k = 0; k < PT; ++k) {
        int i = tid * PT + k;
        v[k] = (i < nsb) ? bucketCnt[i] : 0;
        s += v[k];
    }
    tmp[tid] = s;
    __syncthreads();
    for (int d = 1; d < 256; d <<= 1) {  // Hillis-Steele inclusive scan
        int val = (tid >= d) ? tmp[tid - d] : 0;
        __syncthreads();
        tmp[tid] += val;
        __syncthreads();
    }
    int run = tmp[tid] - s;
    for (int k = 0; k < PT; ++k) {
        int i = tid * PT + k;
        if (i < nsb) bucketOff[i] = run;
        run += v[k];
    }
    if (tid == 255) { bucketOff[nsb] = E; rowptr[N] = E; }
}

// 4) per-bucket scan over PB block-histogram entries -> absolute block cursors.
__global__ void __launch_bounds__(256) k_scanBlk(const int* __restrict__ bucketOff,
                                                 const int* __restrict__ blkHist,
                                                 int* __restrict__ blkCur) {
    __shared__ int tmp[PB];
    const int i = blockIdx.x, t = threadIdx.x;
    int v = blkHist[i * PB + t];
    tmp[t] = v;
    __syncthreads();
    for (int d = 1; d < PB; d <<= 1) {
        int val = (t >= d) ? tmp[t - d] : 0;
        __syncthreads();
        tmp[t] += val;
        __syncthreads();
    }
    blkCur[i * PB + t] = bucketOff[i] + tmp[t] - v;
}

// 5) partition pass B: scatter with LDS cursors preloaded from blkCur.
//    No global atomics; part[pos] = (row << 8) | (col & 255).
__global__ void __launch_bounds__(256) k_p2b(const int* __restrict__ row,
                                             const int* __restrict__ col,
                                             const int* __restrict__ blkCur,
                                             int* __restrict__ part, int E, int nsb) {
    __shared__ int lcur[NSB_MAX];
    const int tid = threadIdx.x, b = blockIdx.x;
    const int chunkE = (E + PB - 1) / PB;
    const int s = b * chunkE, e = min(s + chunkE, E);
    for (int i = tid; i < nsb; i += 256) lcur[i] = blkCur[i * PB + b];
    __syncthreads();
    for (int j = s + tid; j < e; j += 256) {
        int c = col[j];
        int pos = atomicAdd(&lcur[c >> SBSH], 1);
        part[pos] = (row[j] << SBSH) | (c & (SBN - 1));
    }
}

// 6) within-bucket: LDS per-node histogram -> local scan -> rowptr + dinv +
//    counting sort into eRow. Block owns its bucket; no global atomics.
__global__ void __launch_bounds__(256) k_sortb(const int* __restrict__ bucketOff,
                                               const int* __restrict__ part,
                                               int* __restrict__ rowptr,
                                               float* __restrict__ dinv,
                                               int* __restrict__ eRow, int N) {
    __shared__ int hcnt[SBN];
    __shared__ int tmp[SBN];
    __shared__ int cur[SBN];
    const int tid = threadIdx.x;
    const int base = blockIdx.x << SBSH;
    const int s = bucketOff[blockIdx.x];
    const int e = bucketOff[blockIdx.x + 1];

    hcnt[tid] = 0;
    __syncthreads();
    for (int j = s + tid; j < e; j += 256) atomicAdd(&hcnt[part[j] & (SBN - 1)], 1);
    __syncthreads();
    const int c = hcnt[tid];
    tmp[tid] = c;
    __syncthreads();
    for (int d = 1; d < 256; d <<= 1) {  // Hillis-Steele inclusive scan
        int val = (tid >= d) ? tmp[tid - d] : 0;
        __syncthreads();
        tmp[tid] += val;
        __syncthreads();
    }
    const int myBase = s + tmp[tid] - c;  // exclusive
    cur[tid] = myBase;
    const int n = base + tid;
    if (n < N) {
        rowptr[n] = myBase;
        dinv[n] = __frsqrt_rn((float)(c + 1));
    }
    __syncthreads();
    for (int j = s + tid; j < e; j += 256) {
        int p = part[j];
        int pos = atomicAdd(&cur[p & (SBN - 1)], 1);
        eRow[pos] = p >> SBSH;
    }
}

// 7) xs = (x @ W) * dinv[n]  — register-tiled fp32 GEMM.
//    Epilogue packs bf16x2 SLICE-MAJOR: xsb[slice][node][4 uints], slice = tnI.
//    Each 1.6 MB slice table is XCD-L2-resident for k_aggs.
__global__ void __launch_bounds__(256) k_gemm(const float* __restrict__ x,
                                              const float* __restrict__ W,
                                              const float* __restrict__ dinv,
                                              unsigned* __restrict__ xsb, int N) {
    __shared__ float xT[32][260];
    __shared__ float Wl[32][64];
    const int t = threadIdx.x;
    const int tmI = t >> 3;
    const int tnI = t & 7;
    const int nodeBase = blockIdx.x * 256;

    float acc[8][8] = {};

    for (int k0 = 0; k0 < IN_DIM; k0 += 32) {
#pragma unroll
        for (int i = 0; i < 2; ++i) {
            int flat = i * 256 + t;
            float4 wv = ((const float4*)W)[k0 * 16 + flat];
            *(float4*)&Wl[flat >> 4][(flat & 15) << 2] = wv;
        }
#pragma unroll
        for (int i = 0; i < 8; ++i) {
            int flat = i * 256 + t;
            int n = flat >> 3;
            int kq = (flat & 7) << 2;
            int gn = nodeBase + n;
            if (gn >= N) gn = N - 1;
            float4 v = *(const float4*)(x + (size_t)gn * IN_DIM + k0 + kq);
            xT[kq + 0][n] = v.x;
            xT[kq + 1][n] = v.y;
            xT[kq + 2][n] = v.z;
            xT[kq + 3][n] = v.w;
        }
        __syncthreads();
#pragma unroll
        for (int k = 0; k < 32; ++k) {
            float xv[8], wv[8];
            *(float4*)&xv[0] = *(const float4*)&xT[k][tmI * 8];
            *(float4*)&xv[4] = *(const float4*)&xT[k][tmI * 8 + 4];
            *(float4*)&wv[0] = *(const float4*)&Wl[k][tnI * 8];
            *(float4*)&wv[4] = *(const float4*)&Wl[k][tnI * 8 + 4];
#pragma unroll
            for (int mi = 0; mi < 8; ++mi)
#pragma unroll
                for (int ni = 0; ni < 8; ++ni)
                    acc[mi][ni] = fmaf(xv[mi], wv[ni], acc[mi][ni]);
        }
        __syncthreads();
    }

#pragma unroll
    for (int mi = 0; mi < 8; ++mi) {
        int n = nodeBase + tmI * 8 + mi;
        if (n < N) {
            float d = dinv[n];
            uint4 o;
            o.x = bf16r(acc[mi][0] * d) | (bf16r(acc[mi][1] * d) << 16);
            o.y = bf16r(acc[mi][2] * d) | (bf16r(acc[mi][3] * d) << 16);
            o.z = bf16r(acc[mi][4] * d) | (bf16r(acc[mi][5] * d) << 16);
            o.w = bf16r(acc[mi][6] * d) | (bf16r(acc[mi][7] * d) << 16);
            // slice-major: slice = tnI, 4 uints per node
            *(uint4*)(xsb + ((size_t)tnI * N + n) * 4) = o;
        }
    }
}

// 8) XCD-sliced gather-aggregate. Block -> slice = bid & 7 (XCD round-robin),
//    node group = bid >> 3. One wave per node: 16 edges x 4 uint-cols per iter,
//    butterfly reduce over lane bits 2..5. Gather hits the XCD's own 1.6 MB
//    L2-resident slice table.
__global__ void __launch_bounds__(256) k_aggs(const int* __restrict__ rowptr,
                                              const int* __restrict__ eRow,
                                              const unsigned* __restrict__ xsb,
                                              const float* __restrict__ dinv,
                                              const float* __restrict__ bias,
                                              float* __restrict__ out, int N) {
    const int slice = blockIdx.x & (NSLICE - 1);
    const int n = (blockIdx.x >> 3) * 4 + (threadIdx.x >> 6);
    if (n >= N) return;
    const int j = threadIdx.x & 63;
    const int g = j >> 2;              // edge group 0..15
    const int q = j & 3;               // uint-col within slice
    const unsigned* tab = xsb + (size_t)slice * N * 4;

    const int s = rowptr[n], e = rowptr[n + 1];
    float sx = 0.f, sy = 0.f;
    for (int base = s; base < e; base += 16) {
        int idx = base + g;
        unsigned u = 0;
        if (idx < e) {
            int r = eRow[idx];
            u = tab[(size_t)r * 4 + q];
        }
        sx += blo(u); sy += bhi(u);
    }
    // butterfly over the 16 edge groups (lane bits 2..5)
#pragma unroll
    for (int m = 4; m < 64; m <<= 1) {
        sx += __shfl_xor(sx, m, 64);
        sy += __shfl_xor(sy, m, 64);
    }
    if (j < 4) {
        unsigned us = tab[(size_t)n * 4 + q];  // self-loop term
        sx += blo(us); sy += bhi(us);
        const float d = dinv[n];
        const float2 bl = *(const float2*)&bias[slice * 8 + q * 2];
        float2 o;
        o.x = fmaxf(fmaf(sx, d, bl.x), 0.f);
        o.y = fmaxf(fmaf(sy, d, bl.y), 0.f);
        *(float2*)(out + (size_t)n * HID + slice * 8 + q * 2) = o;
    }
}

extern "C" void kernel_launch(void* const* d_in, const int* in_sizes, int n_in,
                              void* d_out, int out_size, void* d_ws, size_t ws_size,
                              hipStream_t stream) {
    const float* x  = (const float*)d_in[0];
    const int*   ei = (const int*)d_in[1];
    const float* W  = (const float*)d_in[2];
    const float* b  = (const float*)d_in[3];
    float* out = (float*)d_out;

    const int N = in_sizes[0] / IN_DIM;
    const int E = in_sizes[1] / 2;
    const int* row = ei;      // edge_index[0] = sources
    const int* col = ei + E;  // edge_index[1] = destinations
    const int NSB = (N + SBN - 1) >> SBSH;

    // workspace (4-byte units), ~41 MB:
    // bucketCnt[NSB] | bucketOff[NSB+1] | rowptr[N+1] | dinv[N] | xsb[8][N][4]
    // | part[E] | eRow[E] | blkHist[NSB*PB] | blkCur[NSB*PB]
    int*      bucketCnt = (int*)d_ws;
    int*      bucketOff = bucketCnt + NSB;
    int*      rowptr    = bucketOff + NSB + 1;
    float*    dinv      = (float*)(rowptr + N + 1);
    unsigned* xsb       = (unsigned*)(dinv + N);
    int*      part      = (int*)(xsb + (size_t)N * (HID / 2));
    int*      eRow      = part + E;
    int*      blkHist   = eRow + E;
    int*      blkCur    = blkHist + NSB * PB;

    k_zero<<<(NSB + 255) / 256, 256, 0, stream>>>(bucketCnt, NSB);
    k_p2a<<<PB, 256, 0, stream>>>(col, bucketCnt, blkHist, E, NSB);
    k_scanB<<<1, 256, 0, stream>>>(bucketCnt, bucketOff, rowptr, NSB, N, E);
    k_scanBlk<<<NSB, PB, 0, stream>>>(bucketOff, blkHist, blkCur);
    k_p2b<<<PB, 256, 0, stream>>>(row, col, blkCur, part, E, NSB);
    k_sortb<<<NSB, 256, 0, stream>>>(bucketOff, part, rowptr, dinv, eRow, N);
    k_gemm<<<(N + 255) / 256, 256, 0, stream>>>(x, W, dinv, xsb, N);
    k_aggs<<<((N + 3) / 4) * NSLICE, 256, 0, stream>>>(rowptr, eRow, xsb, dinv, b, out, N);
}

// Round 10
// 445.334 us; speedup vs baseline: 1.2226x; 1.2226x over previous
//
#include <hip/hip_runtime.h>

#define IN_DIM 256
#define HID 64
#define SBSH 8             // log2(nodes per super-bucket)
#define SBN 256            // nodes per super-bucket
#define NSB_MAX 512        // LDS array bound (covers N <= 131072)
#define PB 256             // partition blocks (chunk count) — must match p2a/p2b
#define NPASS 4            // column-phase tables; each [N][8 uints] = 3.2 MB (L2-fit)

// round-to-nearest-even fp32 -> bf16 bits
static __device__ __forceinline__ unsigned bf16r(float f) {
    unsigned x = __float_as_uint(f);
    return (x + 0x7fffu + ((x >> 16) & 1u)) >> 16;
}

static __device__ __forceinline__ float blo(unsigned u) { return __uint_as_float(u << 16); }
static __device__ __forceinline__ float bhi(unsigned u) { return __uint_as_float(u & 0xffff0000u); }

// ---------------------------------------------------------------------------
// 1) zero the coarse bucket counters (tiny)
__global__ void __launch_bounds__(256) k_zero(int* __restrict__ p, int n) {
    int i = blockIdx.x * 256 + threadIdx.x;
    if (i < n) p[i] = 0;
}

// 2) partition pass A: per-block LDS histogram over super-buckets.
//    Stores blkHist[bucket][block] and accumulates bucketCnt (one atomic per
//    (block,bucket) ~ 100K total). Single edge-list read.
__global__ void __launch_bounds__(256) k_p2a(const int* __restrict__ col,
                                             int* __restrict__ bucketCnt,
                                             int* __restrict__ blkHist, int E, int nsb) {
    __shared__ int hist[NSB_MAX];
    const int tid = threadIdx.x, b = blockIdx.x;
    const int chunkE = (E + PB - 1) / PB;
    const int s = b * chunkE, e = min(s + chunkE, E);
    for (int i = tid; i < nsb; i += 256) hist[i] = 0;
    __syncthreads();
    for (int j = s + tid; j < e; j += 256) atomicAdd(&hist[col[j] >> SBSH], 1);
    __syncthreads();
    for (int i = tid; i < nsb; i += 256) {
        int h = hist[i];
        blkHist[i * PB + b] = h;
        if (h) atomicAdd(&bucketCnt[i], h);
    }
}

// 3) single-block exclusive scan of bucketCnt[nsb] -> bucketOff; seeds rowptr[N]=E.
__global__ void __launch_bounds__(256) k_scanB(const int* __restrict__ bucketCnt,
                                               int* __restrict__ bucketOff,
                                               int* __restrict__ rowptr,
                                               int nsb, int N, int E) {
    __shared__ int tmp[256];
    const int tid = threadIdx.x;
    const int PT = (nsb + 255) >> 8;
    int v[8];
    int s = 0;
    for (int k = 0; k < PT; ++k) {
        int i = tid * PT + k;
        v[k] = (i < nsb) ? bucketCnt[i] : 0;
        s += v[k];
    }
    tmp[tid] = s;
    __syncthreads();
    for (int d = 1; d < 256; d <<= 1) {  // Hillis-Steele inclusive scan
        int val = (tid >= d) ? tmp[tid - d] : 0;
        __syncthreads();
        tmp[tid] += val;
        __syncthreads();
    }
    int run = tmp[tid] - s;
    for (int k = 0; k < PT; ++k) {
        int i = tid * PT + k;
        if (i < nsb) bucketOff[i] = run;
        run += v[k];
    }
    if (tid == 255) { bucketOff[nsb] = E; rowptr[N] = E; }
}

// 4) per-bucket scan over PB block-histogram entries -> absolute block cursors.
__global__ void __launch_bounds__(256) k_scanBlk(const int* __restrict__ bucketOff,
                                                 const int* __restrict__ blkHist,
                                                 int* __restrict__ blkCur) {
    __shared__ int tmp[PB];
    const int i = blockIdx.x, t = threadIdx.x;
    int v = blkHist[i * PB + t];
    tmp[t] = v;
    __syncthreads();
    for (int d = 1; d < PB; d <<= 1) {
        int val = (t >= d) ? tmp[t - d] : 0;
        __syncthreads();
        tmp[t] += val;
        __syncthreads();
    }
    blkCur[i * PB + t] = bucketOff[i] + tmp[t] - v;
}

// 5) partition pass B: scatter with LDS cursors preloaded from blkCur.
//    No global atomics; part[pos] = (row << 8) | (col & 255).
__global__ void __launch_bounds__(256) k_p2b(const int* __restrict__ row,
                                             const int* __restrict__ col,
                                             const int* __restrict__ blkCur,
                                             int* __restrict__ part, int E, int nsb) {
    __shared__ int lcur[NSB_MAX];
    const int tid = threadIdx.x, b = blockIdx.x;
    const int chunkE = (E + PB - 1) / PB;
    const int s = b * chunkE, e = min(s + chunkE, E);
    for (int i = tid; i < nsb; i += 256) lcur[i] = blkCur[i * PB + b];
    __syncthreads();
    for (int j = s + tid; j < e; j += 256) {
        int c = col[j];
        int pos = atomicAdd(&lcur[c >> SBSH], 1);
        part[pos] = (row[j] << SBSH) | (c & (SBN - 1));
    }
}

// 6) within-bucket: LDS per-node histogram -> local scan -> rowptr + dinv +
//    counting sort into eRow. Block owns its bucket; no global atomics.
__global__ void __launch_bounds__(256) k_sortb(const int* __restrict__ bucketOff,
                                               const int* __restrict__ part,
                                               int* __restrict__ rowptr,
                                               float* __restrict__ dinv,
                                               int* __restrict__ eRow, int N) {
    __shared__ int hcnt[SBN];
    __shared__ int tmp[SBN];
    __shared__ int cur[SBN];
    const int tid = threadIdx.x;
    const int base = blockIdx.x << SBSH;
    const int s = bucketOff[blockIdx.x];
    const int e = bucketOff[blockIdx.x + 1];

    hcnt[tid] = 0;
    __syncthreads();
    for (int j = s + tid; j < e; j += 256) atomicAdd(&hcnt[part[j] & (SBN - 1)], 1);
    __syncthreads();
    const int c = hcnt[tid];
    tmp[tid] = c;
    __syncthreads();
    for (int d = 1; d < 256; d <<= 1) {  // Hillis-Steele inclusive scan
        int val = (tid >= d) ? tmp[tid - d] : 0;
        __syncthreads();
        tmp[tid] += val;
        __syncthreads();
    }
    const int myBase = s + tmp[tid] - c;  // exclusive
    cur[tid] = myBase;
    const int n = base + tid;
    if (n < N) {
        rowptr[n] = myBase;
        dinv[n] = __frsqrt_rn((float)(c + 1));
    }
    __syncthreads();
    for (int j = s + tid; j < e; j += 256) {
        int p = part[j];
        int pos = atomicAdd(&cur[p & (SBN - 1)], 1);
        eRow[pos] = p >> SBSH;
    }
}

// 7) xs = (x @ W) * dinv[n]  — register-tiled fp32 GEMM.
//    Epilogue packs bf16x2 into NPASS column-phase tables:
//    tab[phase][node][8 uints], phase = cols/16. Each table 3.2 MB (L2-fit).
__global__ void __launch_bounds__(256) k_gemm(const float* __restrict__ x,
                                              const float* __restrict__ W,
                                              const float* __restrict__ dinv,
                                              unsigned* __restrict__ xsb, int N) {
    __shared__ float xT[32][260];
    __shared__ float Wl[32][64];
    const int t = threadIdx.x;
    const int tmI = t >> 3;
    const int tnI = t & 7;
    const int nodeBase = blockIdx.x * 256;

    float acc[8][8] = {};

    for (int k0 = 0; k0 < IN_DIM; k0 += 32) {
#pragma unroll
        for (int i = 0; i < 2; ++i) {
            int flat = i * 256 + t;
            float4 wv = ((const float4*)W)[k0 * 16 + flat];
            *(float4*)&Wl[flat >> 4][(flat & 15) << 2] = wv;
        }
#pragma unroll
        for (int i = 0; i < 8; ++i) {
            int flat = i * 256 + t;
            int n = flat >> 3;
            int kq = (flat & 7) << 2;
            int gn = nodeBase + n;
            if (gn >= N) gn = N - 1;
            float4 v = *(const float4*)(x + (size_t)gn * IN_DIM + k0 + kq);
            xT[kq + 0][n] = v.x;
            xT[kq + 1][n] = v.y;
            xT[kq + 2][n] = v.z;
            xT[kq + 3][n] = v.w;
        }
        __syncthreads();
#pragma unroll
        for (int k = 0; k < 32; ++k) {
            float xv[8], wv[8];
            *(float4*)&xv[0] = *(const float4*)&xT[k][tmI * 8];
            *(float4*)&xv[4] = *(const float4*)&xT[k][tmI * 8 + 4];
            *(float4*)&wv[0] = *(const float4*)&Wl[k][tnI * 8];
            *(float4*)&wv[4] = *(const float4*)&Wl[k][tnI * 8 + 4];
#pragma unroll
            for (int mi = 0; mi < 8; ++mi)
#pragma unroll
                for (int ni = 0; ni < 8; ++ni)
                    acc[mi][ni] = fmaf(xv[mi], wv[ni], acc[mi][ni]);
        }
        __syncthreads();
    }

    // thread covers cols [tnI*8, tnI*8+8) = global uints [tnI*4, tnI*4+4)
    const int phase = tnI >> 1;           // table index
    const int qoff  = (tnI & 1) * 4;      // uint offset within table row
#pragma unroll
    for (int mi = 0; mi < 8; ++mi) {
        int n = nodeBase + tmI * 8 + mi;
        if (n < N) {
            float d = dinv[n];
            uint4 o;
            o.x = bf16r(acc[mi][0] * d) | (bf16r(acc[mi][1] * d) << 16);
            o.y = bf16r(acc[mi][2] * d) | (bf16r(acc[mi][3] * d) << 16);
            o.z = bf16r(acc[mi][4] * d) | (bf16r(acc[mi][5] * d) << 16);
            o.w = bf16r(acc[mi][6] * d) | (bf16r(acc[mi][7] * d) << 16);
            *(uint4*)(xsb + ((size_t)phase * N + n) * 8 + qoff) = o;
        }
    }
}

// 8) column-phase gather-aggregate (R8 wave shape, 1/4 columns per launch).
//    Wave = 2 nodes x 32 lanes; lane = (uint-col q 0..7, edge-slot 0..3).
//    Each slot walks a contiguous quarter of the node's edge list, ILP-4.
//    The phase's 3.2 MB table is L2-resident on every XCD during the pass.
__global__ void __launch_bounds__(256) k_aggp(const int* __restrict__ rowptr,
                                              const int* __restrict__ eRow,
                                              const unsigned* __restrict__ tab,
                                              const float* __restrict__ dinv,
                                              const float* __restrict__ bias,
                                              float* __restrict__ out, int N, int colbase) {
    const int l = threadIdx.x & 63;
    const int q = l & 7;                 // uint column within table
    const int slot = (l >> 3) & 3;       // edge-list quarter
    const int n = (blockIdx.x * 4 + (threadIdx.x >> 6)) * 2 + (l >> 5);
    if (n >= N) return;

    const int s = rowptr[n], e = rowptr[n + 1];
    const int quarter = (e - s + 3) >> 2;
    const int js = s + slot * quarter;
    const int je = min(js + quarter, e);

    float sx = 0.f, sy = 0.f;
    int j = js;
    for (; j + 3 < je; j += 4) {
        int r0 = eRow[j], r1 = eRow[j + 1], r2 = eRow[j + 2], r3 = eRow[j + 3];
        unsigned u0 = tab[(size_t)r0 * 8 + q];
        unsigned u1 = tab[(size_t)r1 * 8 + q];
        unsigned u2 = tab[(size_t)r2 * 8 + q];
        unsigned u3 = tab[(size_t)r3 * 8 + q];
        sx += (blo(u0) + blo(u1)) + (blo(u2) + blo(u3));
        sy += (bhi(u0) + bhi(u1)) + (bhi(u2) + bhi(u3));
    }
    for (; j < je; ++j) {
        unsigned u0 = tab[(size_t)eRow[j] * 8 + q];
        sx += blo(u0); sy += bhi(u0);
    }
    // combine the 4 edge-slots (lane bits 3,4 — stays within each node's 32 lanes)
    sx += __shfl_xor(sx, 8, 64);  sy += __shfl_xor(sy, 8, 64);
    sx += __shfl_xor(sx, 16, 64); sy += __shfl_xor(sy, 16, 64);

    if (slot == 0) {
        unsigned us = tab[(size_t)n * 8 + q];  // self-loop term
        sx += blo(us); sy += bhi(us);
        const float d = dinv[n];
        const float2 bl = *(const float2*)&bias[colbase + 2 * q];
        float2 o;
        o.x = fmaxf(fmaf(sx, d, bl.x), 0.f);
        o.y = fmaxf(fmaf(sy, d, bl.y), 0.f);
        *(float2*)(out + (size_t)n * HID + colbase + 2 * q) = o;
    }
}

extern "C" void kernel_launch(void* const* d_in, const int* in_sizes, int n_in,
                              void* d_out, int out_size, void* d_ws, size_t ws_size,
                              hipStream_t stream) {
    const float* x  = (const float*)d_in[0];
    const int*   ei = (const int*)d_in[1];
    const float* W  = (const float*)d_in[2];
    const float* b  = (const float*)d_in[3];
    float* out = (float*)d_out;

    const int N = in_sizes[0] / IN_DIM;
    const int E = in_sizes[1] / 2;
    const int* row = ei;      // edge_index[0] = sources
    const int* col = ei + E;  // edge_index[1] = destinations
    const int NSB = (N + SBN - 1) >> SBSH;

    // workspace (4-byte units), ~41 MB:
    // bucketCnt[NSB] | bucketOff[NSB+1] | rowptr[N+1] | dinv[N] | xsb[4][N][8]
    // | part[E] | eRow[E] | blkHist[NSB*PB] | blkCur[NSB*PB]
    int*      bucketCnt = (int*)d_ws;
    int*      bucketOff = bucketCnt + NSB;
    int*      rowptr    = bucketOff + NSB + 1;
    float*    dinv      = (float*)(rowptr + N + 1);
    unsigned* xsb       = (unsigned*)(dinv + N);
    int*      part      = (int*)(xsb + (size_t)N * (HID / 2));
    int*      eRow      = part + E;
    int*      blkHist   = eRow + E;
    int*      blkCur    = blkHist + NSB * PB;

    k_zero<<<(NSB + 255) / 256, 256, 0, stream>>>(bucketCnt, NSB);
    k_p2a<<<PB, 256, 0, stream>>>(col, bucketCnt, blkHist, E, NSB);
    k_scanB<<<1, 256, 0, stream>>>(bucketCnt, bucketOff, rowptr, NSB, N, E);
    k_scanBlk<<<NSB, PB, 0, stream>>>(bucketOff, blkHist, blkCur);
    k_p2b<<<PB, 256, 0, stream>>>(row, col, blkCur, part, E, NSB);
    k_sortb<<<NSB, 256, 0, stream>>>(bucketOff, part, rowptr, dinv, eRow, N);
    k_gemm<<<(N + 255) / 256, 256, 0, stream>>>(x, W, dinv, xsb, N);
    for (int p = 0; p < NPASS; ++p) {
        const unsigned* tabp = xsb + (size_t)p * N * 8;
        k_aggp<<<(N + 7) / 8, 256, 0, stream>>>(rowptr, eRow, tabp, dinv, b, out, N, p * 16);
    }
}